// Round 1
// baseline (692.379 us; speedup 1.0000x reference)
//
#include <hip/hip_runtime.h>
#include <utility>
#include <cstddef>

// GMM E-step: N=200000 points, K=16 components, D=64 dims, fp32.
// Kernel 1: per-component Cholesky + triangular inverse + constants (tiny).
// Kernel 2: per-point Mahalanobis (packed-triangular W, scalar-fed FMAs) + softmax.

#define GMM_D 64
#define GMM_K 16
#define GMM_TRI 2080  // 64*65/2

// ---------------------------------------------------------------------------
// Precompute: one block (64 threads = 1 wave) per component.
// ---------------------------------------------------------------------------
__global__ __launch_bounds__(64) void gmm_precompute_kernel(
    const float* __restrict__ pi, const float* __restrict__ mus,
    const float* __restrict__ covs, float* __restrict__ Wp,
    float* __restrict__ tv, float* __restrict__ cc)
{
    const int k = blockIdx.x;
    const int i = threadIdx.x;  // row (and later: column) owned by this lane

    __shared__ float L[GMM_D][GMM_D + 1];
    __shared__ float Ws[GMM_D][GMM_D + 1];

    // load covariance row i
    for (int j = 0; j < GMM_D; ++j) L[i][j] = covs[k * GMM_D * GMM_D + i * GMM_D + j];
    __syncthreads();

    // Cholesky (Crout, column by column). Lane i handles row i.
    for (int j = 0; j < GMM_D; ++j) {
        float s = L[i][j];
        for (int p = 0; p < j; ++p) s -= L[i][p] * L[j][p];
        const float dj = sqrtf(__shfl(s, j));
        const float lij = (i == j) ? dj : ((i > j) ? s / dj : 0.0f);
        __syncthreads();   // all reads of column j done before overwrite
        L[i][j] = lij;
        __syncthreads();
    }

    // W = L^{-1} (lower triangular). Lane c computes column c independently
    // (column c only depends on earlier rows of the SAME column).
    {
        const int c = i;
        for (int r = 0; r < GMM_D; ++r) {
            float val;
            if (r < c) {
                val = 0.0f;
            } else {
                float s = (r == c) ? 1.0f : 0.0f;
                for (int j = c; j < r; ++j) s -= L[r][j] * Ws[j][c];
                val = s / L[r][r];
            }
            Ws[r][c] = val;
        }
    }
    __syncthreads();

    // t_i = (W mu)_i  (row i, triangular)
    float ti = 0.0f;
    for (int j = 0; j <= i; ++j) ti += Ws[i][j] * mus[k * GMM_D + j];
    tv[k * GMM_D + i] = ti;

    // packed-triangular W, row-major: row i at offset i(i+1)/2
    const int base = k * GMM_TRI + (i * (i + 1)) / 2;
    for (int j = 0; j <= i; ++j) Wp[base + j] = Ws[i][j];

    // c_k = log pi_k - sum(log L_ii) - 0.5*D*log(2*pi)
    float ll = logf(L[i][i]);
    for (int off = 32; off > 0; off >>= 1) ll += __shfl_down(ll, off);
    if (i == 0)
        cc[k] = logf(pi[k]) - ll - 0.5f * 64.0f * 1.8378770664093453f;
}

// ---------------------------------------------------------------------------
// Main E-step kernel. One thread = one point. x[] in VGPRs, so ALL indices
// into it must be compile-time constants -> force full unroll via templates.
// W is read via wave-uniform addresses -> scalar loads feed v_fma directly.
// ---------------------------------------------------------------------------
template <int I>
__device__ __forceinline__ void gmm_row(const float* __restrict__ Wk,
                                        const float* __restrict__ tk,
                                        const float (&x)[GMM_D], float& maha)
{
    float z = -tk[I];
    constexpr int base = (I * (I + 1)) / 2;
    #pragma unroll
    for (int j = 0; j <= I; ++j) z = fmaf(Wk[base + j], x[j], z);
    maha = fmaf(z, z, maha);
}

template <int... Is>
__device__ __forceinline__ float gmm_maha(const float* __restrict__ Wk,
                                          const float* __restrict__ tk,
                                          const float (&x)[GMM_D],
                                          std::integer_sequence<int, Is...>)
{
    float maha = 0.0f;
    (gmm_row<Is>(Wk, tk, x, maha), ...);
    return maha;
}

__global__ __launch_bounds__(256) void gmm_estep_kernel(
    const float* __restrict__ X, const float* __restrict__ Wp,
    const float* __restrict__ tv, const float* __restrict__ cc,
    float* __restrict__ out, int N)
{
    // per-thread 16 log-weights; LDS because the rolled k-loop index is
    // dynamic (register arrays need compile-time indices). stride 17 to
    // spread banks.
    __shared__ float wbuf[256 * 17];

    const int n = blockIdx.x * 256 + threadIdx.x;
    if (n >= N) return;  // no __syncthreads in this kernel -> safe early exit

    float x[GMM_D];
    const float4* xp = reinterpret_cast<const float4*>(X + (size_t)n * GMM_D);
    #pragma unroll
    for (int q = 0; q < GMM_D / 4; ++q) {
        const float4 v = xp[q];
        x[4 * q + 0] = v.x; x[4 * q + 1] = v.y;
        x[4 * q + 2] = v.z; x[4 * q + 3] = v.w;
    }

    float* wrow = &wbuf[threadIdx.x * 17];

    #pragma unroll 1   // keep code size small: body is ~2080 FMAs
    for (int k = 0; k < GMM_K; ++k) {
        const float* Wk = Wp + k * GMM_TRI;
        const float* tk = tv + k * GMM_D;
        const float maha =
            gmm_maha(Wk, tk, x, std::make_integer_sequence<int, GMM_D>{});
        wrow[k] = cc[k] - 0.5f * maha;
    }

    // softmax over K=16
    float m = -INFINITY;
    #pragma unroll
    for (int k = 0; k < GMM_K; ++k) m = fmaxf(m, wrow[k]);
    float e[GMM_K];
    float s = 0.0f;
    #pragma unroll
    for (int k = 0; k < GMM_K; ++k) {
        e[k] = __expf(wrow[k] - m);
        s += e[k];
    }
    const float inv = 1.0f / s;

    float4* op = reinterpret_cast<float4*>(out + (size_t)n * GMM_K);
    #pragma unroll
    for (int q = 0; q < GMM_K / 4; ++q) {
        float4 v;
        v.x = e[4 * q + 0] * inv;
        v.y = e[4 * q + 1] * inv;
        v.z = e[4 * q + 2] * inv;
        v.w = e[4 * q + 3] * inv;
        op[q] = v;
    }
}

// ---------------------------------------------------------------------------
extern "C" void kernel_launch(void* const* d_in, const int* in_sizes, int n_in,
                              void* d_out, int out_size, void* d_ws, size_t ws_size,
                              hipStream_t stream)
{
    const float* X    = (const float*)d_in[0];
    const float* pi   = (const float*)d_in[1];
    const float* mus  = (const float*)d_in[2];
    const float* covs = (const float*)d_in[3];
    float* out = (float*)d_out;

    const int N = in_sizes[0] / GMM_D;

    // workspace layout: packed W [K*2080] | t [K*64] | c [K]  (~137 KB)
    float* Wp = (float*)d_ws;
    float* tv = Wp + GMM_K * GMM_TRI;
    float* cc = tv + GMM_K * GMM_D;

    gmm_precompute_kernel<<<dim3(GMM_K), dim3(64), 0, stream>>>(pi, mus, covs, Wp, tv, cc);

    const int blocks = (N + 255) / 256;
    gmm_estep_kernel<<<dim3(blocks), dim3(256), 0, stream>>>(X, Wp, tv, cc, out, N);
}